// Round 14
// baseline (121.356 us; speedup 1.0000x reference)
//
#include <hip/hip_runtime.h>
#include <cstdint>

#define CKDIM 128
#define MDIM  4096
#define QDIM  4096
#define BATCH 4

typedef __attribute__((ext_vector_type(8)))  _Float16 half8;
typedef __attribute__((ext_vector_type(4)))  float    f32x4;
typedef __attribute__((ext_vector_type(16))) float    f32x16;

#if __has_builtin(__builtin_amdgcn_exp2f)
#define EXP2(x) __builtin_amdgcn_exp2f(x)
#else
#define EXP2(x) exp2f(x)
#endif

#define ALPHA 0.12753139626596757f    // log2(e)/sqrt(128)
#define K2A   0.25506279253193514f    // 2*ALPHA

__device__ inline void gl_lds16(const void* g, void* l) {
    __builtin_amdgcn_global_load_lds(
        (const __attribute__((address_space(1))) unsigned*)g,
        (__attribute__((address_space(3))) unsigned*)l, 16, 0, 0);
}

// ---- 1) fused convert (unchanged). Chunked layouts:
//   At: per batch, 64 m-tiles of 64 rows: [tile][c=k/8][m%64][8] (16KB tiles)
//   Bt: per batch, 32 q-stripes of 128:   [stripe][c=k/8][q%128][8] (32KB)
//   cm[b][m] = -ALPHA*sum_k Mk^2 (fp32-exact). Qk half zeroes sums[].
__global__ void convert_kernel(const float* __restrict__ Mk, const float* __restrict__ Qk,
                               _Float16* __restrict__ At, _Float16* __restrict__ Bt,
                               float* __restrict__ cm, float* __restrict__ sums) {
    __shared__ _Float16 T[128 * 130];
    __shared__ float    asqp[16][128];
    const int blk = blockIdx.x;                  // 256: mat(2) x b(4) x tile(32)
    const int mat = blk >> 7;
    const int b   = (blk >> 5) & 3;
    const int t   = blk & 31;
    const float* src = (mat ? Qk : Mk) + (size_t)b * CKDIM * MDIM + t * 128;
    const int tid = threadIdx.x;
    const int kg  = tid >> 4;
    const int ng  = tid & 15;

    float sq[8] = {0.f, 0.f, 0.f, 0.f, 0.f, 0.f, 0.f, 0.f};
    #pragma unroll
    for (int it = 0; it < 8; ++it) {
        int k = it * 16 + kg;
        const float* g = src + (size_t)k * MDIM + ng * 8;
        float4 v0 = *(const float4*)g;
        float4 v1 = *(const float4*)(g + 4);
        _Float16* p = &T[k * 130 + ng * 8];
        p[0] = (_Float16)v0.x; p[1] = (_Float16)v0.y; p[2] = (_Float16)v0.z; p[3] = (_Float16)v0.w;
        p[4] = (_Float16)v1.x; p[5] = (_Float16)v1.y; p[6] = (_Float16)v1.z; p[7] = (_Float16)v1.w;
        if (mat == 0) {
            sq[0] += v0.x * v0.x; sq[1] += v0.y * v0.y;
            sq[2] += v0.z * v0.z; sq[3] += v0.w * v0.w;
            sq[4] += v1.x * v1.x; sq[5] += v1.y * v1.y;
            sq[6] += v1.z * v1.z; sq[7] += v1.w * v1.w;
        }
    }
    if (mat == 0) {
        #pragma unroll
        for (int j = 0; j < 8; ++j) asqp[kg][ng * 8 + j] = sq[j];
    } else {
        if (tid < 128) sums[(blk & 127) * 128 + tid] = 0.f;
    }
    __syncthreads();
    #pragma unroll
    for (int it = 0; it < 8; ++it) {
        int idx = it * 256 + tid;
        int cc  = idx >> 7;
        int n   = idx & 127;
        half8 o;
        #pragma unroll
        for (int j = 0; j < 8; ++j) o[j] = T[(cc * 8 + j) * 130 + n];
        if (mat == 0) {
            _Float16* dst = At + (size_t)b * (MDIM * CKDIM)
                          + (size_t)(t * 2 + (n >> 6)) * 8192 + cc * 512 + (n & 63) * 8;
            *(half8*)dst = o;
        } else {
            _Float16* dst = Bt + (size_t)b * (QDIM * CKDIM)
                          + (size_t)t * 16384 + cc * 1024 + n * 8;
            *(half8*)dst = o;
        }
    }
    if (mat == 0 && tid < 128) {
        float s = 0.f;
        #pragma unroll
        for (int g = 0; g < 16; ++g) s += asqp[g][tid];
        cm[b * MDIM + t * 128 + tid] = -ALPHA * s;
    }
}

// ---- 2/3) GEMM passes: round-11 structure + intra-wave MFMA/VALU pipeline.
// 1024 blocks x 256 thr (4 waves: 2 m-groups x 2 q-groups), LDS-dbuf A tiles,
// B frags in VGPRs. Per tile: MFMA(h0) -> epilogue(prev h1) -> MFMA(h1) ->
// epilogue(h0) so the exp2 VALU work always overlaps a draining MFMA chain.
// lrs = -log2(sum) folded into the exponent; NT full-line stores.
template <int WRITE>
__global__ __launch_bounds__(256, 3) void gemm_pass(
        const _Float16* __restrict__ At, const _Float16* __restrict__ Bt,
        const float* __restrict__ cmArr, float* __restrict__ sums,
        float* __restrict__ out) {
    __shared__ __align__(16) char ldsA[2][16384];
    const int tid  = threadIdx.x;
    const int lane = tid & 63;
    const int wv   = tid >> 6;
    const int mg   = wv >> 1;       // m-group (32 rows)
    const int qg   = wv & 1;        // q-group (64 cols, two 32-col halves)
    const int l5   = lane >> 5;
    const int l31  = lane & 31;

    const int wg = blockIdx.x;
    const int id = ((wg & 7) << 7) | (wg >> 3);     // XCD-chunked, bijective
    const int b  = id >> 8;
    const int qs = (id >> 3) & 31;
    const int ms = id & 7;
    const int q0 = qs << 7;
    const int m0 = ms << 9;

    const char* Ab = (const char*)At + ((size_t)(b * 64 + ms * 8) << 14);  // 16KB tiles
    const char* Bb = (const char*)Bt + ((size_t)(b * 32 + qs) << 15);      // 32KB stripe

    // B fragments -> registers
    half8 bq0[8], bq1[8];
    #pragma unroll
    for (int kk = 0; kk < 8; ++kk) {
        const char* p = Bb + (size_t)(2 * kk + l5) * 2048 + (qg * 64 + l31) * 16;
        bq0[kk] = *(const half8*)(p);
        bq1[kk] = *(const half8*)(p + 512);
    }

    float lrs0 = 0.f, lrs1 = 0.f;
    if (WRITE) {
        lrs0 = -__log2f(sums[(b << 12) + q0 + qg * 64 + l31]);
        lrs1 = -__log2f(sums[(b << 12) + q0 + qg * 64 + 32 + l31]);
    }

    const int cmbase = (b << 12) + m0 + mg * 32 + l5 * 4;
    float cs0 = 0.f, cs1 = 0.f;

    // epilogue for one 32-col half of one tile's accumulator
    auto EP = [&](const f32x16& ac, int t, int h) {
        #pragma unroll
        for (int j = 0; j < 4; ++j) {
            f32x4 cmj = *(const f32x4*)&cmArr[cmbase + t * 64 + j * 8];
            if (WRITE) {
                f32x4 c = cmj + (h ? lrs1 : lrs0);
                #pragma unroll
                for (int rr = 0; rr < 4; ++rr) {
                    int    row  = m0 + t * 64 + mg * 32 + j * 8 + rr + l5 * 4;
                    size_t base = ((((size_t)b << 12) + row) << 12) + q0 + qg * 64 + h * 32 + l31;
                    __builtin_nontemporal_store(EXP2(fmaf(ac[j * 4 + rr], K2A, c[rr])), &out[base]);
                }
            } else {
                float& cs = h ? cs1 : cs0;
                #pragma unroll
                for (int rr = 0; rr < 4; ++rr)
                    cs += EXP2(fmaf(ac[j * 4 + rr], K2A, cmj[rr]));
            }
        }
    };

    // stage A tile 0
    #pragma unroll
    for (int r = 0; r < 4; ++r) {
        unsigned Dw = r * 4096u + wv * 1024u;
        gl_lds16(Ab + Dw + lane * 16, ldsA[0] + Dw);
    }
    asm volatile("s_waitcnt vmcnt(0)" ::: "memory");
    __builtin_amdgcn_s_barrier();

    const f32x16 ZERO = {};
    f32x16 accB = ZERO;     // h1 accumulator, persists across tiles

    #pragma unroll
    for (int mt = 0; mt < 8; ++mt) {
        if (mt + 1 < 8) {                    // prefetch next A tile
            const char* Asrc = Ab + ((size_t)(mt + 1) << 14);
            char* dst = ldsA[(mt + 1) & 1];
            #pragma unroll
            for (int r = 0; r < 4; ++r) {
                unsigned Dw = r * 4096u + wv * 1024u;
                gl_lds16(Asrc + Dw + lane * 16, dst + Dw);
            }
        }
        __builtin_amdgcn_sched_barrier(0);

        const char* lA = ldsA[mt & 1];
        half8 a[8];
        #pragma unroll
        for (int kk = 0; kk < 8; ++kk)
            a[kk] = *(const half8*)(lA + (2 * kk + l5) * 1024 + (mg * 32 + l31) * 16);

        // MFMA h0
        f32x16 accA = ZERO;
        __builtin_amdgcn_s_setprio(1);
        #pragma unroll
        for (int kk = 0; kk < 8; ++kk)
            accA = __builtin_amdgcn_mfma_f32_32x32x16_f16(a[kk], bq0[kk], accA, 0, 0, 0);
        __builtin_amdgcn_s_setprio(0);
        __builtin_amdgcn_sched_barrier(0);

        if (mt > 0) EP(accB, mt - 1, 1);     // prev tile h1 epilogue ∥ h0 chain
        __builtin_amdgcn_sched_barrier(0);

        // MFMA h1
        accB = ZERO;
        __builtin_amdgcn_s_setprio(1);
        #pragma unroll
        for (int kk = 0; kk < 8; ++kk)
            accB = __builtin_amdgcn_mfma_f32_32x32x16_f16(a[kk], bq1[kk], accB, 0, 0, 0);
        __builtin_amdgcn_s_setprio(0);
        __builtin_amdgcn_sched_barrier(0);

        EP(accA, mt, 0);                     // h0 epilogue ∥ h1 chain

        if (mt + 1 < 8) {
            // guarantee the 4 prefetch gl_lds landed; leave newer cm loads
            // (retired) and the 32 NT stores (pass1) in flight.
            if (WRITE) asm volatile("s_waitcnt vmcnt(40)" ::: "memory");
            else       asm volatile("s_waitcnt vmcnt(0)"  ::: "memory");
            __builtin_amdgcn_s_barrier();
            __builtin_amdgcn_sched_barrier(0);
        }
    }
    EP(accB, 7, 1);                          // tail epilogue

    if (!WRITE) {
        cs0 += __shfl_xor(cs0, 32);
        cs1 += __shfl_xor(cs1, 32);
        if (lane < 32) {
            __hip_atomic_fetch_add(&sums[(b << 12) + q0 + qg * 64 + lane], cs0,
                                   __ATOMIC_RELAXED, __HIP_MEMORY_SCOPE_AGENT);
            __hip_atomic_fetch_add(&sums[(b << 12) + q0 + qg * 64 + 32 + lane], cs1,
                                   __ATOMIC_RELAXED, __HIP_MEMORY_SCOPE_AGENT);
        }
    }
}

extern "C" void kernel_launch(void* const* d_in, const int* in_sizes, int n_in,
                              void* d_out, int out_size, void* d_ws, size_t ws_size,
                              hipStream_t stream) {
    const float* Mk = (const float*)d_in[0];
    const float* Qk = (const float*)d_in[1];
    float* out = (float*)d_out;

    _Float16* At   = (_Float16*)d_ws;                               // 4 MB
    _Float16* Bt   = At + (size_t)BATCH * MDIM * CKDIM;             // 4 MB
    float*    sums = (float*)(Bt + (size_t)BATCH * MDIM * CKDIM);   // 64 KB
    float*    cm   = sums + BATCH * QDIM;                           // 64 KB

    convert_kernel<<<256, 256, 0, stream>>>(Mk, Qk, At, Bt, cm, sums);
    gemm_pass<0><<<1024, 256, 0, stream>>>(At, Bt, cm, sums, out);
    gemm_pass<1><<<1024, 256, 0, stream>>>(At, Bt, cm, sums, out);
}

// Round 15
// 103.439 us; speedup vs baseline: 1.1732x; 1.1732x over previous
//
#include <hip/hip_runtime.h>
#include <cstdint>

#define CKDIM 128
#define MDIM  4096
#define QDIM  4096
#define BATCH 4

typedef __attribute__((ext_vector_type(8)))  _Float16 half8;
typedef __attribute__((ext_vector_type(4)))  float    f32x4;
typedef __attribute__((ext_vector_type(16))) float    f32x16;

#if __has_builtin(__builtin_amdgcn_exp2f)
#define EXP2(x) __builtin_amdgcn_exp2f(x)
#else
#define EXP2(x) exp2f(x)
#endif

#define ALPHA 0.12753139626596757f    // log2(e)/sqrt(128)
#define K2A   0.25506279253193514f    // 2*ALPHA

__device__ inline void gl_lds16(const void* g, void* l) {
    __builtin_amdgcn_global_load_lds(
        (const __attribute__((address_space(1))) unsigned*)g,
        (__attribute__((address_space(3))) unsigned*)l, 16, 0, 0);
}

// ---- 1) fused convert (unchanged from round 11). Chunked layouts:
//   At: per batch, 64 m-tiles of 64 rows: [tile][c=k/8][m%64][8] (16KB tiles)
//   Bt: per batch, 32 q-stripes of 128:   [stripe][c=k/8][q%128][8] (32KB)
//   cm[b][m] = -ALPHA*sum_k Mk^2 (fp32-exact). Qk half zeroes sums[].
__global__ void convert_kernel(const float* __restrict__ Mk, const float* __restrict__ Qk,
                               _Float16* __restrict__ At, _Float16* __restrict__ Bt,
                               float* __restrict__ cm, float* __restrict__ sums) {
    __shared__ _Float16 T[128 * 130];
    __shared__ float    asqp[16][128];
    const int blk = blockIdx.x;                  // 256: mat(2) x b(4) x tile(32)
    const int mat = blk >> 7;
    const int b   = (blk >> 5) & 3;
    const int t   = blk & 31;
    const float* src = (mat ? Qk : Mk) + (size_t)b * CKDIM * MDIM + t * 128;
    const int tid = threadIdx.x;
    const int kg  = tid >> 4;
    const int ng  = tid & 15;

    float sq[8] = {0.f, 0.f, 0.f, 0.f, 0.f, 0.f, 0.f, 0.f};
    #pragma unroll
    for (int it = 0; it < 8; ++it) {
        int k = it * 16 + kg;
        const float* g = src + (size_t)k * MDIM + ng * 8;
        float4 v0 = *(const float4*)g;
        float4 v1 = *(const float4*)(g + 4);
        _Float16* p = &T[k * 130 + ng * 8];
        p[0] = (_Float16)v0.x; p[1] = (_Float16)v0.y; p[2] = (_Float16)v0.z; p[3] = (_Float16)v0.w;
        p[4] = (_Float16)v1.x; p[5] = (_Float16)v1.y; p[6] = (_Float16)v1.z; p[7] = (_Float16)v1.w;
        if (mat == 0) {
            sq[0] += v0.x * v0.x; sq[1] += v0.y * v0.y;
            sq[2] += v0.z * v0.z; sq[3] += v0.w * v0.w;
            sq[4] += v1.x * v1.x; sq[5] += v1.y * v1.y;
            sq[6] += v1.z * v1.z; sq[7] += v1.w * v1.w;
        }
    }
    if (mat == 0) {
        #pragma unroll
        for (int j = 0; j < 8; ++j) asqp[kg][ng * 8 + j] = sq[j];
    } else {
        if (tid < 128) sums[(blk & 127) * 128 + tid] = 0.f;
    }
    __syncthreads();
    #pragma unroll
    for (int it = 0; it < 8; ++it) {
        int idx = it * 256 + tid;
        int cc  = idx >> 7;
        int n   = idx & 127;
        half8 o;
        #pragma unroll
        for (int j = 0; j < 8; ++j) o[j] = T[(cc * 8 + j) * 130 + n];
        if (mat == 0) {
            _Float16* dst = At + (size_t)b * (MDIM * CKDIM)
                          + (size_t)(t * 2 + (n >> 6)) * 8192 + cc * 512 + (n & 63) * 8;
            *(half8*)dst = o;
        } else {
            _Float16* dst = Bt + (size_t)b * (QDIM * CKDIM)
                          + (size_t)t * 16384 + cc * 1024 + n * 8;
            *(half8*)dst = o;
        }
    }
    if (mat == 0 && tid < 128) {
        float s = 0.f;
        #pragma unroll
        for (int g = 0; g < 16; ++g) s += asqp[g][tid];
        cm[b * MDIM + t * 128 + tid] = -ALPHA * s;
    }
}

// ---- 2/3) GEMM passes: round-11 structure + WITHIN-TILE MFMA/VALU
// interleave. Per tile: chain h0 (8 MFMA) -> chain h1 with 2 epilogue
// elements of h0 placed after each MFMA (VALU issues inside the dependent
// chain's stall slots; sched_barrier(0) pins each slot) -> epilogue h1.
// cmv preloaded per tile BEFORE the prefetch so its wait is vmcnt(4).
// Gates: pass0 vmcnt(0); pass1 vmcnt(32) (4 gl_lds oldest, 32 NT stores
// newest). NT full-line stores. #pragma unroll 1 on the tile loop.
template <int WRITE>
__global__ __launch_bounds__(256, 3) void gemm_pass(
        const _Float16* __restrict__ At, const _Float16* __restrict__ Bt,
        const float* __restrict__ cmArr, float* __restrict__ sums,
        float* __restrict__ out) {
    __shared__ __align__(16) char ldsA[2][16384];
    const int tid  = threadIdx.x;
    const int lane = tid & 63;
    const int wv   = tid >> 6;
    const int mg   = wv >> 1;       // m-group (32 rows)
    const int qg   = wv & 1;        // q-group (64 cols = two 32-col halves)
    const int l5   = lane >> 5;
    const int l31  = lane & 31;

    const int wg = blockIdx.x;
    const int id = ((wg & 7) << 7) | (wg >> 3);     // XCD-chunked, bijective
    const int b  = id >> 8;
    const int qs = (id >> 3) & 31;
    const int ms = id & 7;
    const int q0 = qs << 7;
    const int m0 = ms << 9;

    const char* Ab = (const char*)At + ((size_t)(b * 64 + ms * 8) << 14);  // 16KB tiles
    const char* Bb = (const char*)Bt + ((size_t)(b * 32 + qs) << 15);      // 32KB stripe

    // B fragments -> registers
    half8 bq0[8], bq1[8];
    #pragma unroll
    for (int kk = 0; kk < 8; ++kk) {
        const char* p = Bb + (size_t)(2 * kk + l5) * 2048 + (qg * 64 + l31) * 16;
        bq0[kk] = *(const half8*)(p);
        bq1[kk] = *(const half8*)(p + 512);
    }

    float rs0 = 0.f, rs1 = 0.f;
    if (WRITE) {
        rs0 = 1.0f / sums[(b << 12) + q0 + qg * 64 + l31];
        rs1 = 1.0f / sums[(b << 12) + q0 + qg * 64 + 32 + l31];
    }

    // stage A tile 0
    #pragma unroll
    for (int r = 0; r < 4; ++r) {
        unsigned Dw = r * 4096u + wv * 1024u;
        gl_lds16(Ab + Dw + lane * 16, ldsA[0] + Dw);
    }
    asm volatile("s_waitcnt vmcnt(0)" ::: "memory");
    __syncthreads();

    const int cmbase = (b << 12) + m0 + mg * 32 + l5 * 4;
    float cs0 = 0.f, cs1 = 0.f;
    const f32x16 kZero = {};

    #pragma unroll 1
    for (int mt = 0; mt < 8; ++mt) {
        // cmv FIRST (oldest in VMEM FIFO -> its wait leaves prefetch in flight)
        f32x4 cmv[4];
        #pragma unroll
        for (int j = 0; j < 4; ++j)
            cmv[j] = *(const f32x4*)&cmArr[cmbase + mt * 64 + j * 8];
        __builtin_amdgcn_sched_barrier(0);

        if (mt + 1 < 8) {                    // prefetch next A tile
            const char* Asrc = Ab + ((size_t)(mt + 1) << 14);
            char* dst = ldsA[(mt + 1) & 1];
            #pragma unroll
            for (int r = 0; r < 4; ++r) {
                unsigned Dw = r * 4096u + wv * 1024u;
                gl_lds16(Asrc + Dw + lane * 16, dst + Dw);
            }
        }
        __builtin_amdgcn_sched_barrier(0);

        const char* lA = ldsA[mt & 1];
        half8 a[8];
        #pragma unroll
        for (int kk = 0; kk < 8; ++kk)
            a[kk] = *(const half8*)(lA + (2 * kk + l5) * 1024 + (mg * 32 + l31) * 16);

        const size_t obase = ((((size_t)b << 12) + m0 + mt * 64 + mg * 32 + l5 * 4) << 12)
                           + q0 + qg * 64 + l31;

        // one epilogue element: e -> (j = e>>2, rr = e&3)
        auto EPE = [&](const f32x16& ac, int e, float rs, float& cs, int colOff) {
            float x = EXP2(fmaf(ac[e], K2A, cmv[e >> 2][e & 3]));
            if (WRITE)
                __builtin_nontemporal_store(x * rs,
                    &out[obase + ((size_t)(((e >> 2) << 3) + (e & 3)) << 12) + colOff]);
            else
                cs += x;
        };

        // ---- chain h0 (serial; LDS/cm loads hide under it)
        f32x16 accA = kZero;
        __builtin_amdgcn_s_setprio(1);
        #pragma unroll
        for (int kk = 0; kk < 8; ++kk)
            accA = __builtin_amdgcn_mfma_f32_32x32x16_f16(a[kk], bq0[kk], accA, 0, 0, 0);
        __builtin_amdgcn_s_setprio(0);
        __builtin_amdgcn_sched_barrier(0);

        // ---- chain h1 interleaved with epilogue(h0): VALU fills MFMA stalls
        f32x16 accB = kZero;
        #pragma unroll
        for (int kk = 0; kk < 8; ++kk) {
            accB = __builtin_amdgcn_mfma_f32_32x32x16_f16(a[kk], bq1[kk], accB, 0, 0, 0);
            EPE(accA, 2 * kk,     rs0, cs0, 0);
            EPE(accA, 2 * kk + 1, rs0, cs0, 0);
            __builtin_amdgcn_sched_barrier(0);
        }

        // ---- epilogue h1 (exposed tail)
        #pragma unroll
        for (int e = 0; e < 16; ++e)
            EPE(accB, e, rs1, cs1, 32);

        if (mt + 1 < 8) {
            // pass1: 4 gl_lds oldest + 32 NT stores newest outstanding ->
            // vmcnt(32) retires exactly the prefetch; stores stay async.
            if (WRITE) asm volatile("s_waitcnt vmcnt(32)" ::: "memory");
            else       asm volatile("s_waitcnt vmcnt(0)"  ::: "memory");
            __builtin_amdgcn_s_barrier();
            __builtin_amdgcn_sched_barrier(0);
        }
    }

    if (!WRITE) {
        cs0 += __shfl_xor(cs0, 32);
        cs1 += __shfl_xor(cs1, 32);
        if (lane < 32) {
            __hip_atomic_fetch_add(&sums[(b << 12) + q0 + qg * 64 + lane], cs0,
                                   __ATOMIC_RELAXED, __HIP_MEMORY_SCOPE_AGENT);
            __hip_atomic_fetch_add(&sums[(b << 12) + q0 + qg * 64 + 32 + lane], cs1,
                                   __ATOMIC_RELAXED, __HIP_MEMORY_SCOPE_AGENT);
        }
    }
}

extern "C" void kernel_launch(void* const* d_in, const int* in_sizes, int n_in,
                              void* d_out, int out_size, void* d_ws, size_t ws_size,
                              hipStream_t stream) {
    const float* Mk = (const float*)d_in[0];
    const float* Qk = (const float*)d_in[1];
    float* out = (float*)d_out;

    _Float16* At   = (_Float16*)d_ws;                               // 4 MB
    _Float16* Bt   = At + (size_t)BATCH * MDIM * CKDIM;             // 4 MB
    float*    sums = (float*)(Bt + (size_t)BATCH * MDIM * CKDIM);   // 64 KB
    float*    cm   = sums + BATCH * QDIM;                           // 64 KB

    convert_kernel<<<256, 256, 0, stream>>>(Mk, Qk, At, Bt, cm, sums);
    gemm_pass<0><<<1024, 256, 0, stream>>>(At, Bt, cm, sums, out);
    gemm_pass<1><<<1024, 256, 0, stream>>>(At, Bt, cm, sums, out);
}

// Round 16
// 94.008 us; speedup vs baseline: 1.2909x; 1.1003x over previous
//
#include <hip/hip_runtime.h>
#include <cstdint>

#define CKDIM 128
#define MDIM  4096
#define QDIM  4096
#define BATCH 4

typedef __attribute__((ext_vector_type(8)))  _Float16 half8;
typedef __attribute__((ext_vector_type(4)))  float    f32x4;
typedef __attribute__((ext_vector_type(16))) float    f32x16;

#if __has_builtin(__builtin_amdgcn_exp2f)
#define EXP2(x) __builtin_amdgcn_exp2f(x)
#else
#define EXP2(x) exp2f(x)
#endif

#define ALPHA 0.12753139626596757f    // log2(e)/sqrt(128)
#define K2A   0.25506279253193514f    // 2*ALPHA

__device__ inline void gl_lds16(const void* g, void* l) {
    __builtin_amdgcn_global_load_lds(
        (const __attribute__((address_space(1))) unsigned*)g,
        (__attribute__((address_space(3))) unsigned*)l, 16, 0, 0);
}

// ---- 1) fused convert (unchanged from round 11). Chunked layouts:
//   At: per batch, 64 m-tiles of 64 rows: [tile][c=k/8][m%64][8] (16KB tiles)
//   Bt: per batch, 32 q-stripes of 128:   [stripe][c=k/8][q%128][8] (32KB)
//   cm[b][m] = -ALPHA*sum_k Mk^2 (fp32-exact). Qk half zeroes sums[].
__global__ void convert_kernel(const float* __restrict__ Mk, const float* __restrict__ Qk,
                               _Float16* __restrict__ At, _Float16* __restrict__ Bt,
                               float* __restrict__ cm, float* __restrict__ sums) {
    __shared__ _Float16 T[128 * 130];
    __shared__ float    asqp[16][128];
    const int blk = blockIdx.x;                  // 256: mat(2) x b(4) x tile(32)
    const int mat = blk >> 7;
    const int b   = (blk >> 5) & 3;
    const int t   = blk & 31;
    const float* src = (mat ? Qk : Mk) + (size_t)b * CKDIM * MDIM + t * 128;
    const int tid = threadIdx.x;
    const int kg  = tid >> 4;
    const int ng  = tid & 15;

    float sq[8] = {0.f, 0.f, 0.f, 0.f, 0.f, 0.f, 0.f, 0.f};
    #pragma unroll
    for (int it = 0; it < 8; ++it) {
        int k = it * 16 + kg;
        const float* g = src + (size_t)k * MDIM + ng * 8;
        float4 v0 = *(const float4*)g;
        float4 v1 = *(const float4*)(g + 4);
        _Float16* p = &T[k * 130 + ng * 8];
        p[0] = (_Float16)v0.x; p[1] = (_Float16)v0.y; p[2] = (_Float16)v0.z; p[3] = (_Float16)v0.w;
        p[4] = (_Float16)v1.x; p[5] = (_Float16)v1.y; p[6] = (_Float16)v1.z; p[7] = (_Float16)v1.w;
        if (mat == 0) {
            sq[0] += v0.x * v0.x; sq[1] += v0.y * v0.y;
            sq[2] += v0.z * v0.z; sq[3] += v0.w * v0.w;
            sq[4] += v1.x * v1.x; sq[5] += v1.y * v1.y;
            sq[6] += v1.z * v1.z; sq[7] += v1.w * v1.w;
        }
    }
    if (mat == 0) {
        #pragma unroll
        for (int j = 0; j < 8; ++j) asqp[kg][ng * 8 + j] = sq[j];
    } else {
        if (tid < 128) sums[(blk & 127) * 128 + tid] = 0.f;
    }
    __syncthreads();
    #pragma unroll
    for (int it = 0; it < 8; ++it) {
        int idx = it * 256 + tid;
        int cc  = idx >> 7;
        int n   = idx & 127;
        half8 o;
        #pragma unroll
        for (int j = 0; j < 8; ++j) o[j] = T[(cc * 8 + j) * 130 + n];
        if (mat == 0) {
            _Float16* dst = At + (size_t)b * (MDIM * CKDIM)
                          + (size_t)(t * 2 + (n >> 6)) * 8192 + cc * 512 + (n & 63) * 8;
            *(half8*)dst = o;
        } else {
            _Float16* dst = Bt + (size_t)b * (QDIM * CKDIM)
                          + (size_t)t * 16384 + cc * 1024 + n * 8;
            *(half8*)dst = o;
        }
    }
    if (mat == 0 && tid < 128) {
        float s = 0.f;
        #pragma unroll
        for (int g = 0; g < 16; ++g) s += asqp[g][tid];
        cm[b * MDIM + t * 128 + tid] = -ALPHA * s;
    }
}

// ---- 2/3) GEMM passes: round-11 structure. NTIL = 64-row tiles per block.
// pass0: NTIL=4 -> 2048 blocks (5 resident/CU + stream => TLP fills the
// MFMA and VALU pipes across drifting blocks). pass1: NTIL=8 -> 1024 blocks
// (write locality preserved). lrs = -log2(sum) folded into exponent; NT
// full-line stores; colsum uses 2 partial accumulators to break the add
// dependency chain. Gates: pass0 vmcnt(0); pass1 vmcnt(32) (retires the 4
// prefetch gl_lds, leaves the 32 NT stores in flight).
template <int WRITE, int NTIL>
__global__ __launch_bounds__(256, 4) void gemm_pass(
        const _Float16* __restrict__ At, const _Float16* __restrict__ Bt,
        const float* __restrict__ cmArr, float* __restrict__ sums,
        float* __restrict__ out) {
    __shared__ __align__(16) char ldsA[2][16384];
    const int tid  = threadIdx.x;
    const int lane = tid & 63;
    const int wv   = tid >> 6;
    const int mg   = wv >> 1;       // m-group (32 rows)
    const int qg   = wv & 1;        // q-group (64 cols = two 32-col halves)
    const int l5   = lane >> 5;
    const int l31  = lane & 31;

    constexpr int MSEGS = 64 / NTIL;            // m-segs per batch
    constexpr int TOT   = BATCH * 32 * MSEGS;   // total blocks

    const int wg = blockIdx.x;
    const int id = (wg & 7) * (TOT >> 3) + (wg >> 3);   // XCD-chunked, bijective
    const int ms = id % MSEGS;
    const int qs = (id / MSEGS) & 31;
    const int b  = id / (MSEGS * 32);
    const int q0 = qs << 7;
    const int m0 = ms * (NTIL * 64);

    const char* Ab = (const char*)At + ((size_t)(b * 64 + ms * NTIL) << 14); // 16KB tiles
    const char* Bb = (const char*)Bt + ((size_t)(b * 32 + qs) << 15);        // 32KB stripe

    // B fragments -> registers
    half8 bq0[8], bq1[8];
    #pragma unroll
    for (int kk = 0; kk < 8; ++kk) {
        const char* p = Bb + (size_t)(2 * kk + l5) * 2048 + (qg * 64 + l31) * 16;
        bq0[kk] = *(const half8*)(p);
        bq1[kk] = *(const half8*)(p + 512);
    }

    float lrs0 = 0.f, lrs1 = 0.f;
    if (WRITE) {
        lrs0 = -__log2f(sums[(b << 12) + q0 + qg * 64 + l31]);
        lrs1 = -__log2f(sums[(b << 12) + q0 + qg * 64 + 32 + l31]);
    }

    // stage A tile 0
    #pragma unroll
    for (int r = 0; r < 4; ++r) {
        unsigned Dw = r * 4096u + wv * 1024u;
        gl_lds16(Ab + Dw + lane * 16, ldsA[0] + Dw);
    }
    asm volatile("s_waitcnt vmcnt(0)" ::: "memory");
    __syncthreads();

    const int cmbase = (b << 12) + m0 + mg * 32 + l5 * 4;
    float csp0[2] = {0.f, 0.f}, csp1[2] = {0.f, 0.f};

    #pragma unroll 1
    for (int mt = 0; mt < NTIL; ++mt) {
        const char* lA = ldsA[mt & 1];
        if (mt + 1 < NTIL) {                 // prefetch next A tile
            const char* Asrc = Ab + ((size_t)(mt + 1) << 14);
            char* dst = ldsA[(mt + 1) & 1];
            #pragma unroll
            for (int r = 0; r < 4; ++r) {
                unsigned Dw = r * 4096u + wv * 1024u;
                gl_lds16(Asrc + Dw + lane * 16, dst + Dw);
            }
        }
        __builtin_amdgcn_sched_barrier(0);

        f32x16 acc0 = {}, acc1 = {};
        #pragma unroll
        for (int kk = 0; kk < 8; ++kk) {
            half8 a = *(const half8*)(lA + (2 * kk + l5) * 1024 + (mg * 32 + l31) * 16);
            __builtin_amdgcn_s_setprio(1);
            acc0 = __builtin_amdgcn_mfma_f32_32x32x16_f16(a, bq0[kk], acc0, 0, 0, 0);
            acc1 = __builtin_amdgcn_mfma_f32_32x32x16_f16(a, bq1[kk], acc1, 0, 0, 0);
            __builtin_amdgcn_s_setprio(0);
        }

        // C/D: col = l31, row = rr + 8*j + 4*l5  (reg r = j*4+rr)
        if (WRITE) {
            #pragma unroll
            for (int j = 0; j < 4; ++j) {
                f32x4 cmj = *(const f32x4*)&cmArr[cmbase + mt * 64 + j * 8];
                f32x4 c0  = cmj + lrs0;
                f32x4 c1  = cmj + lrs1;
                #pragma unroll
                for (int rr = 0; rr < 4; ++rr) {
                    int    row  = m0 + mt * 64 + mg * 32 + j * 8 + rr + l5 * 4;
                    size_t base = ((((size_t)b << 12) + row) << 12) + q0 + qg * 64 + l31;
                    __builtin_nontemporal_store(EXP2(fmaf(acc0[j * 4 + rr], K2A, c0[rr])), &out[base]);
                    __builtin_nontemporal_store(EXP2(fmaf(acc1[j * 4 + rr], K2A, c1[rr])), &out[base + 32]);
                }
            }
        } else {
            #pragma unroll
            for (int j = 0; j < 4; ++j) {
                f32x4 cmj = *(const f32x4*)&cmArr[cmbase + mt * 64 + j * 8];
                #pragma unroll
                for (int rr = 0; rr < 4; ++rr) {
                    csp0[rr & 1] += EXP2(fmaf(acc0[j * 4 + rr], K2A, cmj[rr]));
                    csp1[rr & 1] += EXP2(fmaf(acc1[j * 4 + rr], K2A, cmj[rr]));
                }
            }
        }

        if (mt + 1 < NTIL) {
            // pass1: 4 gl_lds oldest + 32 NT stores newer -> vmcnt(32)
            // retires exactly the prefetch; stores stay async.
            if (WRITE) asm volatile("s_waitcnt vmcnt(32)" ::: "memory");
            else       asm volatile("s_waitcnt vmcnt(0)"  ::: "memory");
            __builtin_amdgcn_s_barrier();
            __builtin_amdgcn_sched_barrier(0);
        }
    }

    if (!WRITE) {
        float cs0 = csp0[0] + csp0[1];
        float cs1 = csp1[0] + csp1[1];
        cs0 += __shfl_xor(cs0, 32);
        cs1 += __shfl_xor(cs1, 32);
        if (lane < 32) {
            __hip_atomic_fetch_add(&sums[(b << 12) + q0 + qg * 64 + lane], cs0,
                                   __ATOMIC_RELAXED, __HIP_MEMORY_SCOPE_AGENT);
            __hip_atomic_fetch_add(&sums[(b << 12) + q0 + qg * 64 + 32 + lane], cs1,
                                   __ATOMIC_RELAXED, __HIP_MEMORY_SCOPE_AGENT);
        }
    }
}

extern "C" void kernel_launch(void* const* d_in, const int* in_sizes, int n_in,
                              void* d_out, int out_size, void* d_ws, size_t ws_size,
                              hipStream_t stream) {
    const float* Mk = (const float*)d_in[0];
    const float* Qk = (const float*)d_in[1];
    float* out = (float*)d_out;

    _Float16* At   = (_Float16*)d_ws;                               // 4 MB
    _Float16* Bt   = At + (size_t)BATCH * MDIM * CKDIM;             // 4 MB
    float*    sums = (float*)(Bt + (size_t)BATCH * MDIM * CKDIM);   // 64 KB
    float*    cm   = sums + BATCH * QDIM;                           // 64 KB

    convert_kernel<<<256, 256, 0, stream>>>(Mk, Qk, At, Bt, cm, sums);
    gemm_pass<0, 4><<<2048, 256, 0, stream>>>(At, Bt, cm, sums, out);
    gemm_pass<1, 8><<<1024, 256, 0, stream>>>(At, Bt, cm, sums, out);
}

// Round 17
// 90.872 us; speedup vs baseline: 1.3355x; 1.0345x over previous
//
#include <hip/hip_runtime.h>
#include <cstdint>

#define CKDIM 128
#define MDIM  4096
#define QDIM  4096
#define BATCH 4

typedef __attribute__((ext_vector_type(8)))  _Float16 half8;
typedef __attribute__((ext_vector_type(4)))  float    f32x4;
typedef __attribute__((ext_vector_type(16))) float    f32x16;

#if __has_builtin(__builtin_amdgcn_exp2f)
#define EXP2(x) __builtin_amdgcn_exp2f(x)
#else
#define EXP2(x) exp2f(x)
#endif

#define ALPHA 0.12753139626596757f    // log2(e)/sqrt(128)
#define K2A   0.25506279253193514f    // 2*ALPHA

__device__ inline void gl_lds16(const void* g, void* l) {
    __builtin_amdgcn_global_load_lds(
        (const __attribute__((address_space(1))) unsigned*)g,
        (__attribute__((address_space(3))) unsigned*)l, 16, 0, 0);
}

// ---- 1) fused convert (round-11 verbatim). Chunked layouts:
//   At: per batch, 64 m-tiles of 64 rows: [tile][c=k/8][m%64][8] (16KB tiles)
//   Bt: per batch, 32 q-stripes of 128:   [stripe][c=k/8][q%128][8] (32KB)
//   cm[b][m] = -ALPHA*sum_k Mk^2 (fp32-exact). Qk half zeroes sums[].
__global__ void convert_kernel(const float* __restrict__ Mk, const float* __restrict__ Qk,
                               _Float16* __restrict__ At, _Float16* __restrict__ Bt,
                               float* __restrict__ cm, float* __restrict__ sums) {
    __shared__ _Float16 T[128 * 130];
    __shared__ float    asqp[16][128];
    const int blk = blockIdx.x;                  // 256: mat(2) x b(4) x tile(32)
    const int mat = blk >> 7;
    const int b   = (blk >> 5) & 3;
    const int t   = blk & 31;
    const float* src = (mat ? Qk : Mk) + (size_t)b * CKDIM * MDIM + t * 128;
    const int tid = threadIdx.x;
    const int kg  = tid >> 4;
    const int ng  = tid & 15;

    float sq[8] = {0.f, 0.f, 0.f, 0.f, 0.f, 0.f, 0.f, 0.f};
    #pragma unroll
    for (int it = 0; it < 8; ++it) {
        int k = it * 16 + kg;
        const float* g = src + (size_t)k * MDIM + ng * 8;
        float4 v0 = *(const float4*)g;
        float4 v1 = *(const float4*)(g + 4);
        _Float16* p = &T[k * 130 + ng * 8];
        p[0] = (_Float16)v0.x; p[1] = (_Float16)v0.y; p[2] = (_Float16)v0.z; p[3] = (_Float16)v0.w;
        p[4] = (_Float16)v1.x; p[5] = (_Float16)v1.y; p[6] = (_Float16)v1.z; p[7] = (_Float16)v1.w;
        if (mat == 0) {
            sq[0] += v0.x * v0.x; sq[1] += v0.y * v0.y;
            sq[2] += v0.z * v0.z; sq[3] += v0.w * v0.w;
            sq[4] += v1.x * v1.x; sq[5] += v1.y * v1.y;
            sq[6] += v1.z * v1.z; sq[7] += v1.w * v1.w;
        }
    }
    if (mat == 0) {
        #pragma unroll
        for (int j = 0; j < 8; ++j) asqp[kg][ng * 8 + j] = sq[j];
    } else {
        if (tid < 128) sums[(blk & 127) * 128 + tid] = 0.f;
    }
    __syncthreads();
    #pragma unroll
    for (int it = 0; it < 8; ++it) {
        int idx = it * 256 + tid;
        int cc  = idx >> 7;
        int n   = idx & 127;
        half8 o;
        #pragma unroll
        for (int j = 0; j < 8; ++j) o[j] = T[(cc * 8 + j) * 130 + n];
        if (mat == 0) {
            _Float16* dst = At + (size_t)b * (MDIM * CKDIM)
                          + (size_t)(t * 2 + (n >> 6)) * 8192 + cc * 512 + (n & 63) * 8;
            *(half8*)dst = o;
        } else {
            _Float16* dst = Bt + (size_t)b * (QDIM * CKDIM)
                          + (size_t)t * 16384 + cc * 1024 + n * 8;
            *(half8*)dst = o;
        }
    }
    if (mat == 0 && tid < 128) {
        float s = 0.f;
        #pragma unroll
        for (int g = 0; g < 16; ++g) s += asqp[g][tid];
        cm[b * MDIM + t * 128 + tid] = -ALPHA * s;
    }
}

// ---- 2/3) GEMM passes, 32x32x16 MFMA — round-11 structure verbatim.
// 1024 blocks (4/CU), 256 thr = 4 waves (2 m-groups x 2 q-groups).
// Block: b, m-seg 512 (8 tiles of 64), q-stripe 128. B frags in VGPRs;
// A staged in chunked 16KB tiles (linear gl_lds, 512B-contiguous
// conflict-free reads), double-buffered. One A-read feeds 2 MFMAs.
// WRITE=0: colsum atomics (r11 verbatim). WRITE=1: r12-measured epilogue
// (lrs = -log2(sum) folded into exponent, NT full-line stores; 49.6 us).
template <int WRITE>
__global__ __launch_bounds__(256, 4) void gemm_pass(
        const _Float16* __restrict__ At, const _Float16* __restrict__ Bt,
        const float* __restrict__ cmArr, float* __restrict__ sums,
        float* __restrict__ out) {
    __shared__ __align__(16) char ldsA[2][16384];
    const int tid  = threadIdx.x;
    const int lane = tid & 63;
    const int wv   = tid >> 6;      // 0..3
    const int mg   = wv >> 1;       // m-group (32 rows)
    const int qg   = wv & 1;        // q-group (64 cols)
    const int l5   = lane >> 5;     // 0..1
    const int l31  = lane & 31;

    const int wg = blockIdx.x;                      // 0..1023
    const int id = ((wg & 7) << 7) | (wg >> 3);     // XCD-chunked, bijective
    const int b  = id >> 8;
    const int qs = (id >> 3) & 31;
    const int ms = id & 7;
    const int q0 = qs << 7;
    const int m0 = ms << 9;

    const char* Ab = (const char*)At + ((size_t)(b * 64 + ms * 8) << 14);  // 16KB tiles
    const char* Bb = (const char*)Bt + ((size_t)(b * 32 + qs) << 15);      // 32KB stripe

    // B fragments -> registers: frag f covers cols qg*64+f*32+(l31);
    // k-step s (16 k): chunk 2s+l5, 512B-contiguous per 32-lane group.
    half8 bq0[8], bq1[8];
    #pragma unroll
    for (int s = 0; s < 8; ++s) {
        const char* p = Bb + (size_t)(2 * s + l5) * 2048 + (qg * 64 + l31) * 16;
        bq0[s] = *(const half8*)(p);
        bq1[s] = *(const half8*)(p + 512);      // +32 cols
    }

    float lrs0 = 0.f, lrs1 = 0.f;
    if (WRITE) {
        lrs0 = -__log2f(sums[(b << 12) + q0 + qg * 64 + l31]);
        lrs1 = -__log2f(sums[(b << 12) + q0 + qg * 64 + 32 + l31]);
    }

    // stage A tile 0 (linear: LDS layout == global layout)
    #pragma unroll
    for (int r = 0; r < 4; ++r) {
        unsigned Dw = r * 4096u + wv * 1024u;
        gl_lds16(Ab + Dw + lane * 16, ldsA[0] + Dw);
    }
    asm volatile("s_waitcnt vmcnt(0)" ::: "memory");
    __syncthreads();

    const int cmbase = (b << 12) + m0 + mg * 32 + l5 * 4;
    float cs0 = 0.f, cs1 = 0.f;

    #pragma unroll 1
    for (int mt = 0; mt < 8; ++mt) {
        const char* lA = ldsA[mt & 1];
        if (mt + 1 < 8) {
            const char* Asrc = Ab + ((size_t)(mt + 1) << 14);
            char* dst = ldsA[(mt + 1) & 1];
            #pragma unroll
            for (int r = 0; r < 4; ++r) {
                unsigned Dw = r * 4096u + wv * 1024u;
                gl_lds16(Asrc + Dw + lane * 16, dst + Dw);
            }
        }
        __builtin_amdgcn_sched_barrier(0);

        f32x16 acc0 = {}, acc1 = {};
        #pragma unroll
        for (int s = 0; s < 8; ++s) {
            // A frag: chunk 2s+l5, rows mg*32 + l31 -> 512B contiguous
            half8 a = *(const half8*)(lA + (2 * s + l5) * 1024 + (mg * 32 + l31) * 16);
            __builtin_amdgcn_s_setprio(1);
            acc0 = __builtin_amdgcn_mfma_f32_32x32x16_f16(a, bq0[s], acc0, 0, 0, 0);
            acc1 = __builtin_amdgcn_mfma_f32_32x32x16_f16(a, bq1[s], acc1, 0, 0, 0);
            __builtin_amdgcn_s_setprio(0);
        }

        // C/D: col = l31, row = (r&3) + 8*(r>>2) + 4*l5
        if (WRITE) {
            #pragma unroll
            for (int j = 0; j < 4; ++j) {
                f32x4 cmj = *(const f32x4*)&cmArr[cmbase + mt * 64 + j * 8];
                f32x4 c0  = cmj + lrs0;
                f32x4 c1  = cmj + lrs1;
                #pragma unroll
                for (int rr = 0; rr < 4; ++rr) {
                    int    row  = m0 + mt * 64 + mg * 32 + j * 8 + rr + l5 * 4;
                    size_t base = ((((size_t)b << 12) + row) << 12) + q0 + qg * 64 + l31;
                    __builtin_nontemporal_store(EXP2(fmaf(acc0[j * 4 + rr], K2A, c0[rr])), &out[base]);
                    __builtin_nontemporal_store(EXP2(fmaf(acc1[j * 4 + rr], K2A, c1[rr])), &out[base + 32]);
                }
            }
        } else {
            #pragma unroll
            for (int j = 0; j < 4; ++j) {
                f32x4 cmj = *(const f32x4*)&cmArr[cmbase + mt * 64 + j * 8];
                #pragma unroll
                for (int rr = 0; rr < 4; ++rr) {
                    cs0 += EXP2(fmaf(acc0[j * 4 + rr], K2A, cmj[rr]));
                    cs1 += EXP2(fmaf(acc1[j * 4 + rr], K2A, cmj[rr]));
                }
            }
        }

        if (mt + 1 < 8) {
            // gate: retire the 4 prefetch gl_lds (oldest); cm loads and the
            // 32 NT stores stay in flight across the barrier.
            if (WRITE) asm volatile("s_waitcnt vmcnt(36)" ::: "memory");
            else       asm volatile("s_waitcnt vmcnt(4)"  ::: "memory");
            __builtin_amdgcn_s_barrier();
            __builtin_amdgcn_sched_barrier(0);
        }
    }

    if (!WRITE) {
        cs0 += __shfl_xor(cs0, 32);
        cs1 += __shfl_xor(cs1, 32);
        if (lane < 32) {
            __hip_atomic_fetch_add(&sums[(b << 12) + q0 + qg * 64 + lane], cs0,
                                   __ATOMIC_RELAXED, __HIP_MEMORY_SCOPE_AGENT);
            __hip_atomic_fetch_add(&sums[(b << 12) + q0 + qg * 64 + 32 + lane], cs1,
                                   __ATOMIC_RELAXED, __HIP_MEMORY_SCOPE_AGENT);
        }
    }
}

extern "C" void kernel_launch(void* const* d_in, const int* in_sizes, int n_in,
                              void* d_out, int out_size, void* d_ws, size_t ws_size,
                              hipStream_t stream) {
    const float* Mk = (const float*)d_in[0];
    const float* Qk = (const float*)d_in[1];
    float* out = (float*)d_out;

    _Float16* At   = (_Float16*)d_ws;                               // 4 MB
    _Float16* Bt   = At + (size_t)BATCH * MDIM * CKDIM;             // 4 MB
    float*    sums = (float*)(Bt + (size_t)BATCH * MDIM * CKDIM);   // 64 KB
    float*    cm   = sums + BATCH * QDIM;                           // 64 KB

    convert_kernel<<<256, 256, 0, stream>>>(Mk, Qk, At, Bt, cm, sums);
    gemm_pass<0><<<1024, 256, 0, stream>>>(At, Bt, cm, sums, out);
    gemm_pass<1><<<1024, 256, 0, stream>>>(At, Bt, cm, sums, out);
}

// Round 18
// 85.081 us; speedup vs baseline: 1.4264x; 1.0681x over previous
//
#include <hip/hip_runtime.h>
#include <cstdint>

#define CKDIM 128
#define MDIM  4096
#define QDIM  4096
#define BATCH 4

typedef __attribute__((ext_vector_type(8)))  _Float16 half8;
typedef __attribute__((ext_vector_type(4)))  float    f32x4;
typedef __attribute__((ext_vector_type(16))) float    f32x16;

#if __has_builtin(__builtin_amdgcn_exp2f)
#define EXP2(x) __builtin_amdgcn_exp2f(x)
#else
#define EXP2(x) exp2f(x)
#endif

#define ALPHA 0.12753139626596757f    // log2(e)/sqrt(128)
#define K2A   0.25506279253193514f    // 2*ALPHA

__device__ inline void gl_lds16(const void* g, void* l) {
    __builtin_amdgcn_global_load_lds(
        (const __attribute__((address_space(1))) unsigned*)g,
        (__attribute__((address_space(3))) unsigned*)l, 16, 0, 0);
}

// ---- 1) fused convert (round-11 verbatim). Chunked layouts:
//   At: per batch, 64 m-tiles of 64 rows: [tile][c=k/8][m%64][8] (16KB tiles)
//   Bt: per batch, 32 q-stripes of 128:   [stripe][c=k/8][q%128][8] (32KB)
//   cm[b][m] = -ALPHA*sum_k Mk^2 (fp32-exact). Qk half zeroes sums[].
__global__ void convert_kernel(const float* __restrict__ Mk, const float* __restrict__ Qk,
                               _Float16* __restrict__ At, _Float16* __restrict__ Bt,
                               float* __restrict__ cm, float* __restrict__ sums) {
    __shared__ _Float16 T[128 * 130];
    __shared__ float    asqp[16][128];
    const int blk = blockIdx.x;                  // 256: mat(2) x b(4) x tile(32)
    const int mat = blk >> 7;
    const int b   = (blk >> 5) & 3;
    const int t   = blk & 31;
    const float* src = (mat ? Qk : Mk) + (size_t)b * CKDIM * MDIM + t * 128;
    const int tid = threadIdx.x;
    const int kg  = tid >> 4;
    const int ng  = tid & 15;

    float sq[8] = {0.f, 0.f, 0.f, 0.f, 0.f, 0.f, 0.f, 0.f};
    #pragma unroll
    for (int it = 0; it < 8; ++it) {
        int k = it * 16 + kg;
        const float* g = src + (size_t)k * MDIM + ng * 8;
        float4 v0 = *(const float4*)g;
        float4 v1 = *(const float4*)(g + 4);
        _Float16* p = &T[k * 130 + ng * 8];
        p[0] = (_Float16)v0.x; p[1] = (_Float16)v0.y; p[2] = (_Float16)v0.z; p[3] = (_Float16)v0.w;
        p[4] = (_Float16)v1.x; p[5] = (_Float16)v1.y; p[6] = (_Float16)v1.z; p[7] = (_Float16)v1.w;
        if (mat == 0) {
            sq[0] += v0.x * v0.x; sq[1] += v0.y * v0.y;
            sq[2] += v0.z * v0.z; sq[3] += v0.w * v0.w;
            sq[4] += v1.x * v1.x; sq[5] += v1.y * v1.y;
            sq[6] += v1.z * v1.z; sq[7] += v1.w * v1.w;
        }
    }
    if (mat == 0) {
        #pragma unroll
        for (int j = 0; j < 8; ++j) asqp[kg][ng * 8 + j] = sq[j];
    } else {
        if (tid < 128) sums[(blk & 127) * 128 + tid] = 0.f;
    }
    __syncthreads();
    #pragma unroll
    for (int it = 0; it < 8; ++it) {
        int idx = it * 256 + tid;
        int cc  = idx >> 7;
        int n   = idx & 127;
        half8 o;
        #pragma unroll
        for (int j = 0; j < 8; ++j) o[j] = T[(cc * 8 + j) * 130 + n];
        if (mat == 0) {
            _Float16* dst = At + (size_t)b * (MDIM * CKDIM)
                          + (size_t)(t * 2 + (n >> 6)) * 8192 + cc * 512 + (n & 63) * 8;
            *(half8*)dst = o;
        } else {
            _Float16* dst = Bt + (size_t)b * (QDIM * CKDIM)
                          + (size_t)t * 16384 + cc * 1024 + n * 8;
            *(half8*)dst = o;
        }
    }
    if (mat == 0 && tid < 128) {
        float s = 0.f;
        #pragma unroll
        for (int g = 0; g < 16; ++g) s += asqp[g][tid];
        cm[b * MDIM + t * 128 + tid] = -ALPHA * s;
    }
}

// ---- 2/3) GEMM passes, 32x32x16 MFMA — round-11 verbatim (best: 84.9 us).
// 1024 blocks (4/CU), 256 thr = 4 waves (2 m-groups x 2 q-groups).
// Block: b, m-seg 512 (8 tiles of 64), q-stripe 128. B frags in VGPRs;
// A staged in chunked 16KB tiles (linear gl_lds, 512B-contiguous
// conflict-free reads), double-buffered. One A-read feeds 2 MFMAs.
// WRITE=0: colsum atomics. WRITE=1: out = exp2(fma)*rs, PLAIN stores
// (r17 measured: lrs-fold + NT stores cost +6 us — keep rs + plain).
template <int WRITE>
__global__ __launch_bounds__(256, 4) void gemm_pass(
        const _Float16* __restrict__ At, const _Float16* __restrict__ Bt,
        const float* __restrict__ cmArr, float* __restrict__ sums,
        float* __restrict__ out) {
    __shared__ __align__(16) char ldsA[2][16384];
    const int tid  = threadIdx.x;
    const int lane = tid & 63;
    const int wv   = tid >> 6;      // 0..3
    const int mg   = wv >> 1;       // m-group (32 rows)
    const int qg   = wv & 1;        // q-group (64 cols)
    const int l5   = lane >> 5;     // 0..1
    const int l31  = lane & 31;

    const int wg = blockIdx.x;                      // 0..1023
    const int id = ((wg & 7) << 7) | (wg >> 3);     // XCD-chunked, bijective
    const int b  = id >> 8;
    const int qs = (id >> 3) & 31;
    const int ms = id & 7;
    const int q0 = qs << 7;
    const int m0 = ms << 9;

    const char* Ab = (const char*)At + ((size_t)(b * 64 + ms * 8) << 14);  // 16KB tiles
    const char* Bb = (const char*)Bt + ((size_t)(b * 32 + qs) << 15);      // 32KB stripe

    // B fragments -> registers: frag f covers cols qg*64+f*32+(l31);
    // k-step s (16 k): chunk 2s+l5, 512B-contiguous per 32-lane group.
    half8 bq0[8], bq1[8];
    #pragma unroll
    for (int s = 0; s < 8; ++s) {
        const char* p = Bb + (size_t)(2 * s + l5) * 2048 + (qg * 64 + l31) * 16;
        bq0[s] = *(const half8*)(p);
        bq1[s] = *(const half8*)(p + 512);      // +32 cols
    }

    float rs0, rs1;
    if (WRITE) {
        rs0 = 1.0f / sums[(b << 12) + q0 + qg * 64 + l31];
        rs1 = 1.0f / sums[(b << 12) + q0 + qg * 64 + 32 + l31];
    }

    // stage A tile 0 (linear: LDS layout == global layout)
    #pragma unroll
    for (int r = 0; r < 4; ++r) {
        unsigned Dw = r * 4096u + wv * 1024u;
        gl_lds16(Ab + Dw + lane * 16, ldsA[0] + Dw);
    }
    asm volatile("s_waitcnt vmcnt(0)" ::: "memory");
    __syncthreads();

    const int cmbase = (b << 12) + m0 + mg * 32 + l5 * 4;
    float cs0 = 0.f, cs1 = 0.f;

    #pragma unroll 1
    for (int mt = 0; mt < 8; ++mt) {
        const char* lA = ldsA[mt & 1];
        if (mt + 1 < 8) {
            const char* Asrc = Ab + ((size_t)(mt + 1) << 14);
            char* dst = ldsA[(mt + 1) & 1];
            #pragma unroll
            for (int r = 0; r < 4; ++r) {
                unsigned Dw = r * 4096u + wv * 1024u;
                gl_lds16(Asrc + Dw + lane * 16, dst + Dw);
            }
        }
        __builtin_amdgcn_sched_barrier(0);

        f32x16 acc0 = {}, acc1 = {};
        #pragma unroll
        for (int s = 0; s < 8; ++s) {
            // A frag: chunk 2s+l5, rows mg*32 + l31 -> 512B contiguous
            half8 a = *(const half8*)(lA + (2 * s + l5) * 1024 + (mg * 32 + l31) * 16);
            __builtin_amdgcn_s_setprio(1);
            acc0 = __builtin_amdgcn_mfma_f32_32x32x16_f16(a, bq0[s], acc0, 0, 0, 0);
            acc1 = __builtin_amdgcn_mfma_f32_32x32x16_f16(a, bq1[s], acc1, 0, 0, 0);
            __builtin_amdgcn_s_setprio(0);
        }

        // C/D: col = l31, row = (r&3) + 8*(r>>2) + 4*l5
        if (WRITE) {
            #pragma unroll
            for (int j = 0; j < 4; ++j) {
                f32x4 cmj = *(const f32x4*)&cmArr[cmbase + mt * 64 + j * 8];
                #pragma unroll
                for (int rr = 0; rr < 4; ++rr) {
                    int    row  = m0 + mt * 64 + mg * 32 + j * 8 + rr + l5 * 4;
                    size_t base = ((((size_t)b << 12) + row) << 12) + q0 + qg * 64 + l31;
                    out[base]      = EXP2(fmaf(acc0[j * 4 + rr], K2A, cmj[rr])) * rs0;
                    out[base + 32] = EXP2(fmaf(acc1[j * 4 + rr], K2A, cmj[rr])) * rs1;
                }
            }
        } else {
            #pragma unroll
            for (int j = 0; j < 4; ++j) {
                f32x4 cmj = *(const f32x4*)&cmArr[cmbase + mt * 64 + j * 8];
                #pragma unroll
                for (int rr = 0; rr < 4; ++rr) {
                    cs0 += EXP2(fmaf(acc0[j * 4 + rr], K2A, cmj[rr]));
                    cs1 += EXP2(fmaf(acc1[j * 4 + rr], K2A, cmj[rr]));
                }
            }
        }

        if (mt + 1 < 8) {
            // gate: drain everything older than {4 cm + (32 stores)} ->
            // the 4 prefetch gl_lds are guaranteed landed; stores stay async.
            if (WRITE) asm volatile("s_waitcnt vmcnt(36)" ::: "memory");
            else       asm volatile("s_waitcnt vmcnt(4)"  ::: "memory");
            __builtin_amdgcn_s_barrier();
            __builtin_amdgcn_sched_barrier(0);
        }
    }

    if (!WRITE) {
        cs0 += __shfl_xor(cs0, 32);
        cs1 += __shfl_xor(cs1, 32);
        if (lane < 32) {
            __hip_atomic_fetch_add(&sums[(b << 12) + q0 + qg * 64 + lane], cs0,
                                   __ATOMIC_RELAXED, __HIP_MEMORY_SCOPE_AGENT);
            __hip_atomic_fetch_add(&sums[(b << 12) + q0 + qg * 64 + 32 + lane], cs1,
                                   __ATOMIC_RELAXED, __HIP_MEMORY_SCOPE_AGENT);
        }
    }
}

extern "C" void kernel_launch(void* const* d_in, const int* in_sizes, int n_in,
                              void* d_out, int out_size, void* d_ws, size_t ws_size,
                              hipStream_t stream) {
    const float* Mk = (const float*)d_in[0];
    const float* Qk = (const float*)d_in[1];
    float* out = (float*)d_out;

    _Float16* At   = (_Float16*)d_ws;                               // 4 MB
    _Float16* Bt   = At + (size_t)BATCH * MDIM * CKDIM;             // 4 MB
    float*    sums = (float*)(Bt + (size_t)BATCH * MDIM * CKDIM);   // 64 KB
    float*    cm   = sums + BATCH * QDIM;                           // 64 KB

    convert_kernel<<<256, 256, 0, stream>>>(Mk, Qk, At, Bt, cm, sums);
    gemm_pass<0><<<1024, 256, 0, stream>>>(At, Bt, cm, sums, out);
    gemm_pass<1><<<1024, 256, 0, stream>>>(At, Bt, cm, sums, out);
}